// Round 6
// baseline (479.872 us; speedup 1.0000x reference)
//
#include <hip/hip_runtime.h>

// CRF Viterbi decode (B=512, T=512, S=64).
// R5: 4 waves/block (256 thr), one batch/block. Wave w owns prevs
// [16w,16w+16). Phase 1 (lane n = next-tag): gather fv slice via 16
// in-register readlanes from this wave's own merged fv, carry-index ordered
// tree (strict >, left-on-tie = exact jnp first-argmax), publish {val,idx}
// as one ds_write_b64 into an i&1 double-buffered array. ONE barrier.
// Phase 2 (merge domain, lane n -> index myn = 16w + (n&15), redundant x4):
// each wave merges the 4 partials for ITS OWN 16 indices only -> new fv in
// its own registers; no second barrier, no fv LDS round-trip. feat = lg*mk
// prefetched depth-2 in merge domain (never on the chain). Backpointers
// packed 4 tags/dword, written by lanes 0..15 once per 4 steps.
// Backtrace: wave 0 readlane chain (validated bit-exact R1-R4).
// Output: out[0..B) = path_score, out[B + b*(T-1) + t] = (float)tag.

constexpr int Bz = 512;
constexpr int Tz = 512;
constexpr int Sz = 64;
constexpr float NEGINF = -10000.0f;

__device__ __forceinline__ float rlf(float x, int lane) {
    return __int_as_float(__builtin_amdgcn_readlane(__float_as_int(x), lane));
}

__global__ __launch_bounds__(256)
void crf_viterbi_kernel(const float* __restrict__ logits,
                        const float* __restrict__ masks,
                        const float* __restrict__ trans,
                        float* __restrict__ out)
{
    const int n   = threadIdx.x & 63;   // lane id = next-tag (phase 1)
    const int w   = threadIdx.x >> 6;   // wave id 0..3, owns prevs [16w,16w+16)
    const int b   = blockIdx.x;
    const int pb  = 16 * w;
    const int j   = n & 15;             // merge-domain sub-index
    const int myn = pb + j;             // n-index this lane merges

    __shared__ unsigned bp[128 * 64];   // packed backpointers, 32 KB
    __shared__ int2 pvi[2][4][64];      // double-buffered partials {val bits, prev idx}
    __shared__ float ys[Tz - 1];        // emitted tags (backtrace)

    // transitions slice: tr[jj] = trans[n][16w + jj]
    float tr[16];
    {
        const float4* tr4 = reinterpret_cast<const float4*>(trans + n * 64 + pb);
        #pragma unroll
        for (int k = 0; k < 4; ++k) {
            float4 t = tr4[k];
            tr[4 * k + 0] = t.x; tr[4 * k + 1] = t.y;
            tr[4 * k + 2] = t.z; tr[4 * k + 3] = t.w;
        }
    }

    // fv for index myn, held in lane n (valid in all lanes, redundant x4)
    float fvj = (myn == 0) ? 0.0f : NEGINF;

    const float* lgbase = logits + (size_t)b * Tz * Sz;
    const float* mkbase = masks + (size_t)b * Tz;

    // depth-2 prefetch in merge domain: lg0/mk0 for step i, lg1/mk1 for i+1
    float lg0 = lgbase[1 * Sz + myn], lg1 = lgbase[2 * Sz + myn];
    float mk0 = mkbase[1],            mk1 = mkbase[2];

    unsigned pk = 0;
    float psc = 0.0f;

    #pragma unroll 4
    for (int i = 0; i < Tz - 1; ++i) {
        // ---- phase 1: this wave's 16-prev slice for all 64 next-tags ----
        float v[16];
        #pragma unroll
        for (int jj = 0; jj < 16; ++jj)
            v[jj] = rlf(fvj, jj) + tr[jj];

        // carry-index ordered tree (depth 4): strict >, left keeps on tie
        float mv[8]; int mi[8];
        #pragma unroll
        for (int c = 0; c < 8; ++c) {
            bool g = v[2 * c + 1] > v[2 * c];
            mv[c] = g ? v[2 * c + 1] : v[2 * c];
            mi[c] = g ? (2 * c + 1) : (2 * c);
        }
        #pragma unroll
        for (int st = 1; st < 8; st <<= 1) {
            #pragma unroll
            for (int c = 0; c < 8; c += 2 * st) {
                bool g = mv[c + st] > mv[c];
                mv[c] = g ? mv[c + st] : mv[c];
                mi[c] = g ? mi[c + st] : mi[c];
            }
        }
        pvi[i & 1][w][n] = make_int2(__float_as_int(mv[0]), pb + mi[0]);

        __syncthreads();                 // the ONLY barrier per step

        // ---- phase 2 (merge domain): merge 4 partials for index myn ----
        float cv[4]; int ci[4];
        #pragma unroll
        for (int q = 0; q < 4; ++q) {
            int2 p = pvi[i & 1][q][myn];
            cv[q] = __int_as_float(p.x);
            ci[q] = p.y;
        }
        bool g1 = cv[1] > cv[0];
        float m01 = g1 ? cv[1] : cv[0];  int k01 = g1 ? ci[1] : ci[0];
        bool g3 = cv[3] > cv[2];
        float m23 = g3 ? cv[3] : cv[2];  int k23 = g3 ? ci[3] : ci[2];
        bool gm = m23 > m01;
        float m  = gm ? m23 : m01;
        int   gi = gm ? k23 : k01;

        if (i == Tz - 2) psc = m;        // vmaxs[-1] pre-feat (myn==63 lane)

        pk |= ((unsigned)gi) << (8 * (i & 3));
        if ((i & 3) == 3) {
            if (n < 16) bp[(i >> 2) * 64 + myn] = pk;
            pk = 0;
        }

        fvj = m + lg0 * mk0;             // mask multiplies emission only

        // rotate prefetch (off-chain)
        lg0 = lg1; mk0 = mk1;
        int tn = (i + 3 < Tz) ? (i + 3) : (Tz - 1);
        lg1 = lgbase[tn * Sz + myn];
        mk1 = mkbase[tn];
    }

    if (n < 16) bp[127 * 64 + myn] = pk; // flush steps 508..510 (each wave: own 16)
    if (w == 3 && n == 63) out[b] = psc; // path_score = vmaxs[-1][:,63]

    __syncthreads();

    // ---- backtrace (wave 0 only; validated readlane chain) ----
    if (w == 0) {
        unsigned wcur = bp[127 * 64 + n];
        int w127_63 = __builtin_amdgcn_readlane((int)wcur, 63);
        int tag = (w127_63 >> 16) & 255; // t0 = bptrs[510][63]

        for (int g = 127; g >= 0; --g) {
            unsigned wnext = (g > 0) ? bp[(g - 1) * 64 + n] : 0u;  // prefetch
            int smax = (g == 127) ? 2 : 3;
            for (int s = smax; s >= 0; --s) {
                int idx = 4 * g + s;
                if (n == 0) ys[idx] = (float)tag;   // emit BEFORE following ptr
                int wd = __builtin_amdgcn_readlane((int)wcur, tag);
                tag = (wd >> (8 * s)) & 255;
            }
            wcur = wnext;
        }
    }
    __syncthreads();

    float* outseq = out + Bz + (size_t)b * (Tz - 1);
    for (int k = threadIdx.x; k < Tz - 1; k += 256) outseq[k] = ys[k];
}

extern "C" void kernel_launch(void* const* d_in, const int* in_sizes, int n_in,
                              void* d_out, int out_size, void* d_ws, size_t ws_size,
                              hipStream_t stream) {
    const float* logits = (const float*)d_in[0];
    const float* masks  = (const float*)d_in[1];
    const float* trans  = (const float*)d_in[2];
    float* out = (float*)d_out;
    (void)in_sizes; (void)n_in; (void)out_size; (void)d_ws; (void)ws_size;

    crf_viterbi_kernel<<<dim3(Bz), dim3(256), 0, stream>>>(logits, masks, trans, out);
}